// Round 14
// baseline (433.239 us; speedup 1.0000x reference)
//
#include <hip/hip_runtime.h>
#include <hip/hip_bf16.h>
#include <math.h>

#define CCH 256      // channels
#define WROW 264     // LDS weight row stride (shorts): 528B = 4 mod 32 banks (floor pattern)
#define TPB 1024     // 16 waves, 1 block/CU
#define NBLK 256
#define PPB 2048     // points per block (N / NBLK)
#define PPI 256      // points per iteration (8 wave-pairs x 32)
#define NITER 8      // PPB / PPI

typedef __attribute__((ext_vector_type(8))) short short8;
typedef __attribute__((ext_vector_type(4))) float f32x4;
typedef __attribute__((ext_vector_type(2))) float f32x2;
typedef __attribute__((ext_vector_type(4))) unsigned int uint4v;
typedef __attribute__((ext_vector_type(2))) unsigned int uint2v;

// Module-scope device scratch.
__device__ unsigned short g_T0[CCH * CCH];     // T0[n*256+k] = bf16(W_h0[k][n])
__device__ unsigned short g_T1[CCH * CCH];     // T1[n*256+k] = bf16(W_h1[k][n])
__device__ float g_Wof[4 * CCH];               // [j][ch], j<3 real, j=3 zero
__device__ unsigned short g_h1[(size_t)524288 * CCH];  // 268 MB bf16 intermediate

__device__ __forceinline__ unsigned short f2bf(float f) {
  unsigned u = __float_as_uint(f);
  u += 0x7fffu + ((u >> 16) & 1u);   // RNE
  return (unsigned short)(u >> 16);
}
__device__ __forceinline__ unsigned cvtpk(float lo, float hi) {
  unsigned r;
  asm("v_cvt_pk_bf16_f32 %0, %1, %2" : "=v"(r) : "v"(lo), "v"(hi));
  return r;
}

__global__ void transpose_w(const float* __restrict__ W0,
                            const float* __restrict__ W1) {
  __shared__ float tile[32][33];
  const float* src = blockIdx.z ? W1 : W0;
  unsigned short* dst = blockIdx.z ? g_T1 : g_T0;
  const int tx = threadIdx.x, ty = threadIdx.y;       // 32 x 8
  const int k0 = blockIdx.y * 32, n0 = blockIdx.x * 32;
#pragma unroll
  for (int r = 0; r < 4; ++r)
    tile[ty + r * 8][tx] = src[(k0 + ty + r * 8) * CCH + n0 + tx];
  __syncthreads();
#pragma unroll
  for (int r = 0; r < 4; ++r) {
    const int n = n0 + ty + r * 8;
    dst[n * CCH + k0 + tx] = f2bf(tile[tx][ty + r * 8]);
  }
}

__global__ void prep_wof(const float* __restrict__ W_out) {
  const int k = threadIdx.x;   // 256 threads
#pragma unroll
  for (int j = 0; j < 4; ++j)
    g_Wof[j * CCH + k] = (j < 3) ? W_out[k * 3 + j] : 0.0f;
}

__global__ __launch_bounds__(TPB, 4) void nerf_persist(
    const float* __restrict__ uv,
    const float* __restrict__ W_in, const float* __restrict__ b_in,
    const float* __restrict__ b_h0, const float* __restrict__ b_h1,
    const float* __restrict__ b_out,
    float* __restrict__ out) {
  __shared__ unsigned short Wlds[CCH][WROW];   // 135168 B: one layer's weights
  __shared__ float scr[16][2][16][3];          // 6144 B: output-reduce scratch

  const int tid = threadIdx.x;
  const int wv = tid >> 6, ln = tid & 63;
  const int l16 = ln & 15, lk8 = ln >> 4;
  const int pg = wv >> 1;                      // point-group 0..7
  const int chbase = (wv & 1) * 128;           // parity channel half
  const long blk0 = (long)blockIdx.x * PPB;
  const float bo0 = b_out[0], bo1 = b_out[1], bo2 = b_out[2];

  // ---- stage T0 into LDS (coalesced global, bank-floor LDS writes) ----
  {
    const int r = tid >> 2, seg = tid & 3;     // 4 threads/row, 128B each
    const uint4v* src = (const uint4v*)&g_T0[r * CCH + seg * 64];
    uint4v* dst = (uint4v*)&Wlds[r][seg * 64];
#pragma unroll
    for (int j = 0; j < 8; ++j) dst[j] = src[j];
  }
  __syncthreads();

  // ============ phase 0: h1 = relu( relu(enc@W_in+b_in) @ W0 + b_h0 ) ======
  for (int it = 0; it < NITER; ++it) {
    const long pt0 = blk0 + it * PPI + pg * 32 + l16;
    const long pt1 = pt0 + 16;
    const f32x2 uva = *(const f32x2*)&uv[pt0 * 2];
    const f32x2 uvb = *(const f32x2*)&uv[pt1 * 2];
    const float e0[4] = {__cosf(uva[0]), __cosf(uva[1]), __sinf(uva[0]), __sinf(uva[1])};
    const float e1[4] = {__cosf(uvb[0]), __cosf(uvb[1]), __sinf(uvb[0]), __sinf(uvb[1])};

    f32x4 acc[2][8];
#pragma unroll
    for (int mt = 0; mt < 2; ++mt)
#pragma unroll
      for (int nt = 0; nt < 8; ++nt)
        acc[mt][nt] = (f32x4){0.f, 0.f, 0.f, 0.f};

#pragma unroll
    for (int kk = 0; kk < 8; ++kk) {
      const int ch = kk * 32 + lk8 * 8;        // this lane's 8 h0-channels
      // layer-0 on the fly (two 4-channel halves to cap register pressure)
      uint4v p0, p1;
#pragma unroll
      for (int h = 0; h < 2; ++h) {
        const int c4 = ch + h * 4;
        const f32x4 w0 = *(const f32x4*)&W_in[0 * CCH + c4];
        const f32x4 w1 = *(const f32x4*)&W_in[1 * CCH + c4];
        const f32x4 w2 = *(const f32x4*)&W_in[2 * CCH + c4];
        const f32x4 w3 = *(const f32x4*)&W_in[3 * CCH + c4];
        const f32x4 bb = *(const f32x4*)&b_in[c4];
        float x0[4], x1[4];
#pragma unroll
        for (int j = 0; j < 4; ++j) {
          x0[j] = fmaxf(bb[j] + e0[0]*w0[j] + e0[1]*w1[j] + e0[2]*w2[j] + e0[3]*w3[j], 0.f);
          x1[j] = fmaxf(bb[j] + e1[0]*w0[j] + e1[1]*w1[j] + e1[2]*w2[j] + e1[3]*w3[j], 0.f);
        }
        p0[h * 2 + 0] = cvtpk(x0[0], x0[1]); p0[h * 2 + 1] = cvtpk(x0[2], x0[3]);
        p1[h * 2 + 0] = cvtpk(x1[0], x1[1]); p1[h * 2 + 1] = cvtpk(x1[2], x1[3]);
      }
      const short8 B0 = *(short8*)&p0;
      const short8 B1 = *(short8*)&p1;
#pragma unroll
      for (int nt = 0; nt < 8; ++nt) {
        const short8 A = *(const short8*)&Wlds[chbase + nt * 16 + l16][ch];
        acc[0][nt] = __builtin_amdgcn_mfma_f32_16x16x32_bf16(A, B0, acc[0][nt], 0, 0, 0);
        acc[1][nt] = __builtin_amdgcn_mfma_f32_16x16x32_bf16(A, B1, acc[1][nt], 0, 0, 0);
      }
    }
    // h1 store: bias + relu + bf16, streaming to HBM
#pragma unroll
    for (int nt = 0; nt < 8; ++nt) {
      const int ch0 = chbase + nt * 16 + lk8 * 4;
      const f32x4 bv = *(const f32x4*)&b_h0[ch0];
#pragma unroll
      for (int mt = 0; mt < 2; ++mt) {
        const long pt = mt ? pt1 : pt0;
        uint2v pk;
        pk[0] = cvtpk(fmaxf(acc[mt][nt][0] + bv[0], 0.f),
                      fmaxf(acc[mt][nt][1] + bv[1], 0.f));
        pk[1] = cvtpk(fmaxf(acc[mt][nt][2] + bv[2], 0.f),
                      fmaxf(acc[mt][nt][3] + bv[3], 0.f));
        *(uint2v*)&g_h1[pt * CCH + ch0] = pk;
      }
    }
  }

  __syncthreads();   // phase boundary: T0 reads done; h1 writes visible to block
  // ---- stage T1 over T0 ----
  {
    const int r = tid >> 2, seg = tid & 3;
    const uint4v* src = (const uint4v*)&g_T1[r * CCH + seg * 64];
    uint4v* dst = (uint4v*)&Wlds[r][seg * 64];
#pragma unroll
    for (int j = 0; j < 8; ++j) dst[j] = src[j];
  }
  __syncthreads();

  // ============ phase 1: out = sigmoid( relu(h1@W1+b_h1) @ W_out + b_out ) ==
  for (int it = 0; it < NITER; ++it) {
    const long pt0 = blk0 + it * PPI + pg * 32 + l16;
    const long pt1 = pt0 + 16;

    f32x4 acc[2][8];
#pragma unroll
    for (int mt = 0; mt < 2; ++mt)
#pragma unroll
      for (int nt = 0; nt < 8; ++nt)
        acc[mt][nt] = (f32x4){0.f, 0.f, 0.f, 0.f};

#pragma unroll
    for (int kk = 0; kk < 8; ++kk) {
      const int ch = kk * 32 + lk8 * 8;
      const short8 B0 = *(const short8*)&g_h1[pt0 * CCH + ch];
      const short8 B1 = *(const short8*)&g_h1[pt1 * CCH + ch];
#pragma unroll
      for (int nt = 0; nt < 8; ++nt) {
        const short8 A = *(const short8*)&Wlds[chbase + nt * 16 + l16][ch];
        acc[0][nt] = __builtin_amdgcn_mfma_f32_16x16x32_bf16(A, B0, acc[0][nt], 0, 0, 0);
        acc[1][nt] = __builtin_amdgcn_mfma_f32_16x16x32_bf16(A, B1, acc[1][nt], 0, 0, 0);
      }
    }

    // h2 = relu(acc + b_h1); fused 3-channel output dot (per-lane partial)
    float s[2][3] = {{0.f, 0.f, 0.f}, {0.f, 0.f, 0.f}};
#pragma unroll
    for (int nt = 0; nt < 8; ++nt) {
      const int ch0 = chbase + nt * 16 + lk8 * 4;
      const f32x4 bv  = *(const f32x4*)&b_h1[ch0];
      const f32x4 wo0 = *(const f32x4*)&g_Wof[0 * CCH + ch0];
      const f32x4 wo1 = *(const f32x4*)&g_Wof[1 * CCH + ch0];
      const f32x4 wo2 = *(const f32x4*)&g_Wof[2 * CCH + ch0];
#pragma unroll
      for (int mt = 0; mt < 2; ++mt)
#pragma unroll
        for (int i = 0; i < 4; ++i) {
          const float h2 = fmaxf(acc[mt][nt][i] + bv[i], 0.f);
          s[mt][0] += h2 * wo0[i];
          s[mt][1] += h2 * wo1[i];
          s[mt][2] += h2 * wo2[i];
        }
    }
    // reduce over the 4 lk8 lanes of this point-column
#pragma unroll
    for (int mt = 0; mt < 2; ++mt)
#pragma unroll
      for (int j = 0; j < 3; ++j) {
        s[mt][j] += __shfl_xor(s[mt][j], 16);
        s[mt][j] += __shfl_xor(s[mt][j], 32);
      }
    if (lk8 == 0) {
#pragma unroll
      for (int mt = 0; mt < 2; ++mt)
#pragma unroll
        for (int j = 0; j < 3; ++j) scr[wv][mt][l16][j] = s[mt][j];
    }
    __syncthreads();
    if ((wv & 1) == 0 && lk8 == 0) {   // combine parity halves, sigmoid, store
#pragma unroll
      for (int mt = 0; mt < 2; ++mt) {
        const long pt = mt ? pt1 : pt0;
        const float t0 = scr[wv][mt][l16][0] + scr[wv + 1][mt][l16][0] + bo0;
        const float t1 = scr[wv][mt][l16][1] + scr[wv + 1][mt][l16][1] + bo1;
        const float t2 = scr[wv][mt][l16][2] + scr[wv + 1][mt][l16][2] + bo2;
        out[pt * 3 + 0] = 1.f / (1.f + __expf(-t0));
        out[pt * 3 + 1] = 1.f / (1.f + __expf(-t1));
        out[pt * 3 + 2] = 1.f / (1.f + __expf(-t2));
      }
    }
    __syncthreads();   // scr reuse guard
  }
}

extern "C" void kernel_launch(void* const* d_in, const int* in_sizes, int n_in,
                              void* d_out, int out_size, void* d_ws, size_t ws_size,
                              hipStream_t stream) {
  const float* uv    = (const float*)d_in[0];
  const float* W_in  = (const float*)d_in[1];
  const float* b_in  = (const float*)d_in[2];
  const float* W_h0  = (const float*)d_in[3];
  const float* b_h0  = (const float*)d_in[4];
  const float* W_h1  = (const float*)d_in[5];
  const float* b_h1  = (const float*)d_in[6];
  const float* W_out = (const float*)d_in[7];
  const float* b_out = (const float*)d_in[8];

  transpose_w<<<dim3(8, 8, 2), dim3(32, 8), 0, stream>>>(W_h0, W_h1);
  prep_wof<<<1, CCH, 0, stream>>>(W_out);
  nerf_persist<<<dim3(NBLK), dim3(TPB), 0, stream>>>(
      uv, W_in, b_in, b_h0, b_h1, b_out, (float*)d_out);
}